// Round 11
// baseline (293.092 us; speedup 1.0000x reference)
//
#include <hip/hip_runtime.h>
#include <math.h>

// ===== R10 (resubmit): ABLATION PROBE =====
// Nine rounds of structurally different kernels all land at 82-151 us with
// every pipe idle (VALU 15%, HBM 8%, LDS trivial, MFMA 0). Stop guessing;
// measure the marginal cost of each phase with 4 sequential dispatches that
// share launch config (BLOCK=1024, GRID=512, same dynamic LDS = same
// occupancy):
//   v_load : streaming loads only            -> pure load floor
//   v_bin  : loads + find_bin + sq           -> FULL minus atomics
//   v_atom : loads + sq + ds_add @ rotating  -> FULL minus find_bin
//   v_full : complete kernel (writes d_out)
// rocprof gives per-dispatch rows; deltas isolate the bottleneck.

#define BLOCK 1024
#define GRID_BLKS 512

// searchsorted(bins, x, 'right') - 1, clipped to [0, nb-1].
// Uniform guess (error <= 1; absmax=0 across R3/R4/R6/R7/R9) + branchless
// fixup from the exact float32 edge pair (single ds_read_b64).
__device__ __forceinline__ int find_bin(const float2* __restrict__ ep, int nb,
                                        float x, float lo, float inv_step) {
    int g = (int)floorf((x - lo) * inv_step);
    g = g < 0 ? 0 : (g > nb - 1 ? nb - 1 : g);
    float2 e = ep[g];
    g += (x >= e.y) ? 1 : 0;
    g -= (x < e.x) ? 1 : 0;
    return g < 0 ? 0 : (g > nb - 1 ? nb - 1 : g);
}

// block-reduce a double and atomicAdd into *sink (one atomic per block)
__device__ __forceinline__ void reduce_sink(double v, double* sink) {
    #pragma unroll
    for (int off = 32; off > 0; off >>= 1) v += __shfl_down(v, off, 64);
    __shared__ double rs[BLOCK / 64];
    int wave = threadIdx.x >> 6, lane = threadIdx.x & 63;
    if (lane == 0) rs[wave] = v;
    __syncthreads();
    if (threadIdx.x == 0) {
        double t = 0.0;
        #pragma unroll
        for (int w = 0; w < BLOCK / 64; ++w) t += rs[w];
        atomicAdd(sink, t);
    }
}

// ---------- V_LOAD: streaming loads only ----------
__global__ void __launch_bounds__(BLOCK, 8)
v_load(const float* __restrict__ input, const float* __restrict__ target,
       long long npair, double* __restrict__ sink)
{
    const float4* in4 = (const float4*)input;
    const float4* tg4 = (const float4*)target;
    const long long S = (long long)gridDim.x * BLOCK;
    long long p = (long long)blockIdx.x * BLOCK + threadIdx.x;
    float acc = 0.0f;
    for (; p + 3 * S < npair; p += 4 * S) {
        float4 I0 = in4[p];         float4 I1 = in4[p + S];
        float4 I2 = in4[p + 2 * S]; float4 I3 = in4[p + 3 * S];
        float4 T0 = tg4[p];         float4 T1 = tg4[p + S];
        float4 T2 = tg4[p + 2 * S]; float4 T3 = tg4[p + 3 * S];
        acc += (I0.x + I0.y + I0.z + I0.w) + (I1.x + I1.y + I1.z + I1.w)
             + (I2.x + I2.y + I2.z + I2.w) + (I3.x + I3.y + I3.z + I3.w)
             + (T0.x + T0.y + T0.z + T0.w) + (T1.x + T1.y + T1.z + T1.w)
             + (T2.x + T2.y + T2.z + T2.w) + (T3.x + T3.y + T3.z + T3.w);
    }
    for (; p < npair; p += S) {
        float4 I = in4[p], T = tg4[p];
        acc += I.x + I.y + I.z + I.w + T.x + T.y + T.z + T.w;
    }
    reduce_sink((double)acc, sink);
}

// ---------- V_BIN: loads + find_bin + sq (no atomics) ----------
__global__ void __launch_bounds__(BLOCK, 8)
v_bin(const float* __restrict__ input, const float* __restrict__ target,
      const float* __restrict__ bins0, const float* __restrict__ bins1,
      int nb, long long npair, double* __restrict__ sink)
{
    extern __shared__ __align__(16) float smem[];
    float2* ep0 = (float2*)smem;
    float2* ep1 = ep0 + nb;
    for (int i = threadIdx.x; i < nb; i += BLOCK) {
        ep0[i] = make_float2(bins0[i], bins0[i + 1]);
        ep1[i] = make_float2(bins1[i], bins1[i + 1]);
    }
    __syncthreads();
    const float lo0 = ep0[0].x, inv0 = (float)nb / (ep0[nb - 1].y - lo0);
    const float lo1 = ep1[0].x, inv1 = (float)nb / (ep1[nb - 1].y - lo1);

    const float4* in4 = (const float4*)input;
    const float4* tg4 = (const float4*)target;
    const long long S = (long long)gridDim.x * BLOCK;
    long long p = (long long)blockIdx.x * BLOCK + threadIdx.x;
    float acc = 0.0f;
    for (; p < npair; p += S) {
        float4 I = in4[p], T = tg4[p];
        float d0 = I.x - T.x, d1 = I.y - T.y;
        float sqA = d0 * d0 + d1 * d1;
        int iA0 = find_bin(ep0, nb, T.x, lo0, inv0);
        int iA1 = find_bin(ep1, nb, T.y, lo1, inv1);
        float d2 = I.z - T.z, d3 = I.w - T.w;
        float sqB = d2 * d2 + d3 * d3;
        int iB0 = find_bin(ep0, nb, T.z, lo0, inv0);
        int iB1 = find_bin(ep1, nb, T.w, lo1, inv1);
        acc += sqA + sqB + 1e-7f * (float)(iA0 + iA1 + iB0 + iB1);
    }
    reduce_sink((double)acc, sink);
}

// ---------- V_ATOM: loads + sq + ds_add at data-independent bin ----------
__global__ void __launch_bounds__(BLOCK, 8)
v_atom(const float* __restrict__ input, const float* __restrict__ target,
       int nb, long long npair, double* __restrict__ sink)
{
    extern __shared__ __align__(16) float smem[];
    float* hist = smem + 4 * nb;       // same offset as v_full's hist
    const int nbnb = nb * nb;
    for (int i = threadIdx.x; i < nbnb; i += BLOCK) hist[i] = 0.0f;
    __syncthreads();

    const float4* in4 = (const float4*)input;
    const float4* tg4 = (const float4*)target;
    const long long S = (long long)gridDim.x * BLOCK;
    long long p = (long long)blockIdx.x * BLOCK + threadIdx.x;
    int c = (threadIdx.x * 977 + blockIdx.x * 131) % nbnb;   // rotating bin
    for (; p < npair; p += S) {
        float4 I = in4[p], T = tg4[p];
        float d0 = I.x - T.x, d1 = I.y - T.y;
        float sqA = d0 * d0 + d1 * d1;
        float d2 = I.z - T.z, d3 = I.w - T.w;
        float sqB = d2 * d2 + d3 * d3;
        atomicAdd(&hist[c], sqA);
        c += 977; if (c >= nbnb) c -= nbnb;
        atomicAdd(&hist[c], sqB);
        c += 977; if (c >= nbnb) c -= nbnb;
    }
    __syncthreads();
    double a = 0.0;
    for (int b = threadIdx.x; b < nbnb; b += BLOCK) a += (double)hist[b];
    reduce_sink(a, sink);
}

// ---------- V_FULL: the real kernel (R6-best structure) ----------
__global__ void __launch_bounds__(BLOCK, 8)
v_full(const float* __restrict__ input, const float* __restrict__ target,
       const float* __restrict__ smoothed,
       const float* __restrict__ bins0, const float* __restrict__ bins1,
       const float* __restrict__ scaling,
       int nb, long long n, long long nelem,
       double* __restrict__ accA, double* __restrict__ accB,
       unsigned int* __restrict__ accM, unsigned int* __restrict__ done_ctr,
       float* __restrict__ out)
{
    extern __shared__ __align__(16) float smem[];
    float2* ep0  = (float2*)smem;
    float2* ep1  = ep0 + nb;
    float*  hist = smem + 4 * nb;
    const int nbnb = nb * nb;
    for (int i = threadIdx.x; i < nbnb; i += BLOCK) hist[i] = 0.0f;
    for (int i = threadIdx.x; i < nb; i += BLOCK) {
        ep0[i] = make_float2(bins0[i], bins0[i + 1]);
        ep1[i] = make_float2(bins1[i], bins1[i + 1]);
    }
    __syncthreads();
    const float lo0 = ep0[0].x, inv0 = (float)nb / (ep0[nb - 1].y - lo0);
    const float lo1 = ep1[0].x, inv1 = (float)nb / (ep1[nb - 1].y - lo1);

    const float4* in4 = (const float4*)input;
    const float4* tg4 = (const float4*)target;
    const long long npair = n >> 1;
    const long long S = (long long)gridDim.x * BLOCK;
    long long p = (long long)blockIdx.x * BLOCK + threadIdx.x;
    for (; p < npair; p += S) {
        float4 I = in4[p], T = tg4[p];
        float d0 = I.x - T.x, d1 = I.y - T.y;
        float sqA = d0 * d0 + d1 * d1;
        int iA0 = find_bin(ep0, nb, T.x, lo0, inv0);
        int iA1 = find_bin(ep1, nb, T.y, lo1, inv1);
        atomicAdd(&hist[iA0 * nb + iA1], sqA);
        float d2 = I.z - T.z, d3 = I.w - T.w;
        float sqB = d2 * d2 + d3 * d3;
        int iB0 = find_bin(ep0, nb, T.z, lo0, inv0);
        int iB1 = find_bin(ep1, nb, T.w, lo1, inv1);
        atomicAdd(&hist[iB0 * nb + iB1], sqB);
    }
    if ((n & 1) && blockIdx.x == 0 && threadIdx.x == 0) {
        long long i = n - 1;
        float t0 = target[2 * i], t1 = target[2 * i + 1];
        float d0 = input[2 * i] - t0, d1 = input[2 * i + 1] - t1;
        float sq = d0 * d0 + d1 * d1;
        int j0 = find_bin(ep0, nb, t0, lo0, inv0);
        int j1 = find_bin(ep1, nb, t1, lo1, inv1);
        atomicAdd(&hist[j0 * nb + j1], sq);
    }
    __syncthreads();

    double A = 0.0, B = 0.0;
    float  m = 0.0f;
    for (int b = threadIdx.x; b < nbnb; b += BLOCK) {
        float h = hist[b];
        float s = smoothed[b];
        float w = 1.0f / s;
        if (isinf(w)) { B += (double)h; }
        else { A += (double)w * (double)h; if (h > 0.0f) m = fmaxf(m, w); }
    }
    #pragma unroll
    for (int off = 32; off > 0; off >>= 1) {
        A += __shfl_down(A, off, 64);
        B += __shfl_down(B, off, 64);
        m = fmaxf(m, __shfl_down(m, off, 64));
    }
    __shared__ double rA[BLOCK / 64], rB[BLOCK / 64];
    __shared__ float  rM[BLOCK / 64];
    int wave = threadIdx.x >> 6, lane = threadIdx.x & 63;
    if (lane == 0) { rA[wave] = A; rB[wave] = B; rM[wave] = m; }
    __syncthreads();
    if (threadIdx.x == 0) {
        double ta = 0.0, tb = 0.0; float tm = 0.0f;
        #pragma unroll
        for (int w2 = 0; w2 < BLOCK / 64; ++w2) {
            ta += rA[w2]; tb += rB[w2]; tm = fmaxf(tm, rM[w2]);
        }
        atomicAdd(accA, ta);
        atomicAdd(accB, tb);
        atomicMax(accM, __float_as_uint(tm));
        __threadfence();
        unsigned int prev = atomicAdd(done_ctr, 1u);
        if (prev == gridDim.x - 1) {
            double Af = atomicAdd(accA, 0.0);
            double Bf = atomicAdd(accB, 0.0);
            float  Mf = __uint_as_float(atomicMax(accM, 0u));
            double v = (double)(*scaling) * (Af + (double)Mf * Bf) / (double)nelem;
            *out = (float)v;
        }
    }
}

extern "C" void kernel_launch(void* const* d_in, const int* in_sizes, int n_in,
                              void* d_out, int out_size, void* d_ws, size_t ws_size,
                              hipStream_t stream) {
    const float* input    = (const float*)d_in[0];
    const float* target   = (const float*)d_in[1];
    const float* smoothed = (const float*)d_in[2];
    const float* bins0    = (const float*)d_in[3];
    const float* bins1    = (const float*)d_in[4];
    const float* scaling  = (const float*)d_in[5];

    const long long nelem = in_sizes[0];
    const long long n     = nelem / 2;
    const long long npair = n / 2;
    const int nb          = in_sizes[3] - 1;

    double*       accA  = (double*)d_ws;                   // @0
    double*       accB  = accA + 1;                        // @8
    unsigned int* accM  = (unsigned int*)(accB + 1);       // @16
    unsigned int* ctr   = accM + 1;                        // @20
    double*       sinkL = (double*)((char*)d_ws + 24);     // @24
    double*       sinkB = (double*)((char*)d_ws + 32);     // @32
    double*       sinkA = (double*)((char*)d_ws + 40);     // @40

    hipMemsetAsync(d_ws, 0, 48, stream);

    long long blocks_needed = (npair + BLOCK - 1) / BLOCK;
    int grid = (int)(blocks_needed < GRID_BLKS ? blocks_needed : GRID_BLKS);
    if (grid < 1) grid = 1;
    size_t shmem = ((size_t)nb * nb + 4 * (size_t)nb) * sizeof(float);

    v_load<<<grid, BLOCK, shmem, stream>>>(input, target, npair, sinkL);
    v_bin <<<grid, BLOCK, shmem, stream>>>(input, target, bins0, bins1,
                                           nb, npair, sinkB);
    v_atom<<<grid, BLOCK, shmem, stream>>>(input, target, nb, npair, sinkA);
    v_full<<<grid, BLOCK, shmem, stream>>>(input, target, smoothed, bins0, bins1,
                                           scaling, nb, n, nelem,
                                           accA, accB, accM, ctr, (float*)d_out);
}